// Round 4
// baseline (606.044 us; speedup 1.0000x reference)
//
#include <hip/hip_runtime.h>
#include <math.h>

#define TOKENS 4096
#define EMBD   1024
#define HID    4096
#define NE     8
#define SLOTC  8320   // padded slot capacity (8192 used)

typedef __attribute__((ext_vector_type(8))) short short8;
typedef __attribute__((ext_vector_type(4))) float f32x4;

#define GLOBAL_PTR(p) ((const __attribute__((address_space(1))) void*)(p))
#define LDS_PTR(p)    ((__attribute__((address_space(3))) void*)(p))

__device__ __forceinline__ unsigned short f2bf(float f) {
  unsigned int u = __float_as_uint(f);
  u += 0x7FFFu + ((u >> 16) & 1u);   // round-to-nearest-even
  return (unsigned short)(u >> 16);
}
__device__ __forceinline__ float bf2f(unsigned short h) {
  return __uint_as_float((unsigned int)h << 16);
}

// exact-GELU via Abramowitz-Stegun 7.1.26 erf (|eps| < 1.5e-7), ~12 VALU ops
__device__ __forceinline__ float fast_gelu(float v) {
  float u = fabsf(v) * 0.70710678118654752f;
  float t = 1.0f / (1.0f + 0.3275911f * u);
  float poly = ((((1.061405429f * t - 1.453152027f) * t + 1.421413741f) * t
                 - 0.284496736f) * t + 0.254829592f) * t;
  float erf_abs = 1.0f - poly * __expf(-u * u);
  float er = (v < 0.0f) ? -erf_abs : erf_abs;
  return 0.5f * v * (1.0f + er);
}

// ---------- fused gate + x fp32->bf16 convert. One wave per token. ----------
__global__ __launch_bounds__(256) void k_gate_cvt(const float* __restrict__ x,
                                                  const float* __restrict__ gw,
                                                  unsigned short* __restrict__ xb,
                                                  int* __restrict__ idx2,
                                                  float* __restrict__ wv) {
  int wave = threadIdx.x >> 6, lane = threadIdx.x & 63;
  int t = blockIdx.x * 4 + wave;
  const float4* xr = (const float4*)(x + (size_t)t * EMBD);   // 256 float4
  ushort4* xbr = (ushort4*)(xb + (size_t)t * EMBD);
  float acc[NE];
#pragma unroll
  for (int e = 0; e < NE; e++) acc[e] = 0.f;
#pragma unroll
  for (int ch = 0; ch < 4; ch++) {
    int i = ch * 64 + lane;
    float4 v = xr[i];
    ushort4 o;
    o.x = f2bf(v.x); o.y = f2bf(v.y); o.z = f2bf(v.z); o.w = f2bf(v.w);
    xbr[i] = o;
    int c = i * 4;
    const float* g0 = gw + (size_t)c * NE;
#pragma unroll
    for (int e = 0; e < NE; e++) acc[e] += v.x * g0[e];
#pragma unroll
    for (int e = 0; e < NE; e++) acc[e] += v.y * g0[NE + e];
#pragma unroll
    for (int e = 0; e < NE; e++) acc[e] += v.z * g0[2 * NE + e];
#pragma unroll
    for (int e = 0; e < NE; e++) acc[e] += v.w * g0[3 * NE + e];
  }
#pragma unroll
  for (int e = 0; e < NE; e++) {
#pragma unroll
    for (int off = 32; off > 0; off >>= 1) acc[e] += __shfl_down(acc[e], off);
  }
  if (lane == 0) {
    float best = -1e30f, second = -1e30f;
    int bi = 0, si = 0;
#pragma unroll
    for (int e = 0; e < NE; e++) {
      float l = acc[e];
      if (l > best) { second = best; si = bi; best = l; bi = e; }
      else if (l > second) { second = l; si = e; }
    }
    float b = expf(second - best);
    float w0 = 1.f / (1.f + b);
    float w1 = b / (1.f + b);
    idx2[2 * t] = bi; idx2[2 * t + 1] = si;
    wv[2 * t] = w0; wv[2 * t + 1] = w1;
  }
}

// ---------- histogram + prefix in one tiny kernel ----------
__global__ __launch_bounds__(256) void k_count(const int* __restrict__ idx2,
                                               int* __restrict__ ctrl) {
  __shared__ int cnt[NE];
  int tid = threadIdx.x;
  if (tid < NE) cnt[tid] = 0;
  __syncthreads();
  for (int i = tid; i < TOKENS * 2; i += 256) atomicAdd(&cnt[idx2[i]], 1);
  __syncthreads();
  if (tid == 0) {
    int off = 0;
#pragma unroll
    for (int e = 0; e < NE; e++) { int c = cnt[e]; ctrl[e] = c; ctrl[8 + e] = off; off += c; }
    ctrl[16] = off;
  }
  if (tid < NE) ctrl[17 + tid] = 0;
}

// ---------- slot assignment: two-level (LDS positions, 8 global atomics/blk) ---
__global__ __launch_bounds__(256) void k_assign(const int* __restrict__ idx2,
                                                int* __restrict__ ctrl,
                                                int* __restrict__ token_list,
                                                int* __restrict__ tok2slot) {
  __shared__ int lpos[NE];
  __shared__ int lbase[NE];
  int tid = threadIdx.x;
  int t = blockIdx.x * 256 + tid;
  if (tid < NE) lpos[tid] = 0;
  __syncthreads();
  int e0 = idx2[2 * t], e1 = idx2[2 * t + 1];
  int p0 = atomicAdd(&lpos[e0], 1);
  int p1 = atomicAdd(&lpos[e1], 1);
  __syncthreads();
  if (tid < NE) lbase[tid] = atomicAdd(&ctrl[17 + tid], lpos[tid]);
  __syncthreads();
  int s0 = ctrl[8 + e0] + lbase[e0] + p0;
  int s1 = ctrl[8 + e1] + lbase[e1] + p1;
  token_list[s0] = t;
  token_list[s1] = t;
  tok2slot[2 * t] = s0;
  tok2slot[2 * t + 1] = s1;
}

// ---------- transpose+convert: in [e][R][C] fp32 -> out [e][C][R] bf16 ----------
__global__ __launch_bounds__(256) void k_trans(const float* __restrict__ in,
                                               unsigned short* __restrict__ out,
                                               int R, int C) {
  __shared__ unsigned short T[64 * 66];   // [col][row], pad 66
  int e = blockIdx.z;
  const float* ine = in + (size_t)e * R * C;
  unsigned short* oute = out + (size_t)e * R * C;
  int r0 = blockIdx.y * 64;
  int c0 = blockIdx.x * 64;
  int tid = threadIdx.x;
  {
    int c4 = tid & 15;          // float4 col chunk
    int rb = tid >> 4;          // 0..15
#pragma unroll
    for (int it = 0; it < 4; it++) {
      int r = rb + 16 * it;
      float4 v = *(const float4*)(ine + (size_t)(r0 + r) * C + c0 + 4 * c4);
      T[(4 * c4 + 0) * 66 + r] = f2bf(v.x);
      T[(4 * c4 + 1) * 66 + r] = f2bf(v.y);
      T[(4 * c4 + 2) * 66 + r] = f2bf(v.z);
      T[(4 * c4 + 3) * 66 + r] = f2bf(v.w);
    }
  }
  __syncthreads();
  {
    int rr = tid & 7;           // 16B chunk along output row
    int cq = tid >> 3;          // 0..31
#pragma unroll
    for (int it = 0; it < 2; it++) {
      int c = cq + 32 * it;     // output row (= input col)
      short8 o;
#pragma unroll
      for (int k = 0; k < 8; k++) o[k] = (short)T[c * 66 + 8 * rr + k];
      *(short8*)(oute + (size_t)(c0 + c) * R + r0 + 8 * rr) = o;
    }
  }
}

// =====================================================================
// 256x256 grouped GEMM, 8 waves (2Mx4N), BK=32, 4-slot LDS ring (128 KiB),
// fine phases: per K-tile 2 phases of 16 MFMA, each phase
// {ds_read || stage 2 gload_lds -> barrier -> lgkmcnt(0) -> setprio+MFMA
//  -> barrier}; vmcnt gate once per K-tile at PH1.
// vmcnt arithmetic (race fix for tail): steady state 12 outstanding ->
// vmcnt(8) drains kt+1's 4. Tail peeled: kt=NT-3 no stage, 8 outstanding
// -> vmcnt(4); kt=NT-2 -> vmcnt(0); kt=NT-1 no gate.
// LDS: A slot s at s*16384 (h0 rows0-127 @0, h1 rows128-255 @8192);
//      B at 65536 + s*16384. Swizzle: chunk' = q ^ ((row>>1)&3);
// staging fetches global chunk (lane&3)^((lane>>3)&3) into linear LDS.
// =====================================================================

#define SB __builtin_amdgcn_sched_barrier(0)

#define STAGE_A(sl, koff) do {                                                                        \
    __builtin_amdgcn_global_load_lds(GLOBAL_PTR(sA0 + (koff)), LDS_PTR(lds + (sl) * 16384 + wave * 1024), 16, 0, 0);        \
    __builtin_amdgcn_global_load_lds(GLOBAL_PTR(sA1 + (koff)), LDS_PTR(lds + (sl) * 16384 + 8192 + wave * 1024), 16, 0, 0); \
  } while (0)
#define STAGE_B(sl, koff) do {                                                                        \
    __builtin_amdgcn_global_load_lds(GLOBAL_PTR(sB0 + (koff)), LDS_PTR(lds + 65536 + (sl) * 16384 + wave * 1024), 16, 0, 0);        \
    __builtin_amdgcn_global_load_lds(GLOBAL_PTR(sB1 + (koff)), LDS_PTR(lds + 65536 + (sl) * 16384 + 8192 + wave * 1024), 16, 0, 0); \
  } while (0)

// phase 0 of K-tile: read A f0-3 + B n0-3, STAGEOP (A-halves of kt+3), MFMA f0-3
#define PH0(sl, STAGEOP) do {                                                                         \
    const char* Ab_ = lds + (sl) * 16384;                                                             \
    const char* Bb_ = lds + 65536 + (sl) * 16384;                                                     \
    _Pragma("unroll")                                                                                 \
    for (int f = 0; f < 4; f++) a_[f] = *(const short8*)(Ab_ + aoff + f * 1024);                      \
    _Pragma("unroll")                                                                                 \
    for (int n = 0; n < 4; n++) b_[n] = *(const short8*)(Bb_ + boff + n * 1024);                      \
    STAGEOP;                                                                                          \
    SB;                                                                                               \
    __builtin_amdgcn_s_barrier();                                                                     \
    SB;                                                                                               \
    asm volatile("s_waitcnt lgkmcnt(0)" ::: "memory");                                                \
    SB;                                                                                               \
    __builtin_amdgcn_s_setprio(1);                                                                    \
    _Pragma("unroll")                                                                                 \
    for (int f = 0; f < 4; f++)                                                                       \
      _Pragma("unroll")                                                                               \
      for (int n = 0; n < 4; n++)                                                                     \
        acc[f][n] = __builtin_amdgcn_mfma_f32_16x16x32_bf16(a_[f], b_[n], acc[f][n], 0, 0, 0);        \
    __builtin_amdgcn_s_setprio(0);                                                                    \
    SB;                                                                                               \
    __builtin_amdgcn_s_barrier();                                                                     \
    SB;                                                                                               \
  } while (0)

// phase 1: read A f4-7 (B reused in regs), STAGEOP (B-halves of kt+3), WAITOP gate
#define PH1(sl, STAGEOP, WAITOP) do {                                                                 \
    const char* Ab_ = lds + (sl) * 16384;                                                             \
    _Pragma("unroll")                                                                                 \
    for (int f = 0; f < 4; f++) a_[f] = *(const short8*)(Ab_ + aoff + (f + 4) * 1024);                \
    STAGEOP;                                                                                          \
    WAITOP;                                                                                           \
    SB;                                                                                               \
    __builtin_amdgcn_s_barrier();                                                                     \
    SB;                                                                                               \
    asm volatile("s_waitcnt lgkmcnt(0)" ::: "memory");                                                \
    SB;                                                                                               \
    __builtin_amdgcn_s_setprio(1);                                                                    \
    _Pragma("unroll")                                                                                 \
    for (int f = 0; f < 4; f++)                                                                       \
      _Pragma("unroll")                                                                               \
      for (int n = 0; n < 4; n++)                                                                     \
        acc[f + 4][n] = __builtin_amdgcn_mfma_f32_16x16x32_bf16(a_[f], b_[n], acc[f + 4][n], 0, 0, 0);\
    __builtin_amdgcn_s_setprio(0);                                                                    \
    SB;                                                                                               \
    __builtin_amdgcn_s_barrier();                                                                     \
    SB;                                                                                               \
  } while (0)

#define VM8 asm volatile("s_waitcnt vmcnt(8)" ::: "memory")
#define VM4 asm volatile("s_waitcnt vmcnt(4)" ::: "memory")
#define VM0 asm volatile("s_waitcnt vmcnt(0)" ::: "memory")
#define NOP (void)0

// ---------- GEMM1: H = gelu(gather(x) @ w1[e] + b1[e]) ----------
// grid 2048: e = h&7 (XCD-keyed); j = h>>3: m_idx = j&15 (fastest), n_idx = j>>4.
__global__ __launch_bounds__(512, 2) void k_gemm1(
    const unsigned short* __restrict__ xb,
    const unsigned short* __restrict__ w1t,
    const float* __restrict__ b1,
    const int* __restrict__ ctrl,
    const int* __restrict__ token_list,
    unsigned short* __restrict__ Hbuf) {
  int h = blockIdx.x;
  int e = h & 7;
  int j = h >> 3;
  int m_base = (j & 15) * 256;
  int nb = (j >> 4) * 256;
  int cnt = ctrl[e];
  if (m_base >= cnt) return;
  int off_e = ctrl[8 + e];
  int tid = threadIdx.x;
  int wave = tid >> 6, lane = tid & 63;
  int wr = wave >> 2, wc = wave & 3;
  int q4 = lane >> 4, cc = lane & 15;

  __shared__ __align__(16) char lds[131072];

  // staging sources (loop-invariant): wave covers 16 rows per half-tile
  int chS = (lane & 3) ^ ((lane >> 3) & 3);
  int row0 = wave * 16 + (lane >> 2);       // rows 0..127 (half 0)
  int row1 = 128 + row0;                    // rows 128..255 (half 1)
  int tok0 = token_list[off_e + min(m_base + row0, cnt - 1)];
  int tok1 = token_list[off_e + min(m_base + row1, cnt - 1)];
  const unsigned short* sA0 = xb + (size_t)tok0 * EMBD + chS * 8;
  const unsigned short* sA1 = xb + (size_t)tok1 * EMBD + chS * 8;
  const unsigned short* wbp = w1t + (size_t)e * HID * EMBD;
  const unsigned short* sB0 = wbp + (size_t)(nb + row0) * EMBD + chS * 8;
  const unsigned short* sB1 = wbp + (size_t)(nb + row1) * EMBD + chS * 8;

  // ds_read byte offsets within slot
  int swz = (q4 ^ ((cc >> 1) & 3)) * 16;
  int aoff = wr * 8192 + cc * 64 + swz;
  int boff = (wc >> 1) * 8192 + (wc & 1) * 4096 + cc * 64 + swz;

  f32x4 acc[8][4];
#pragma unroll
  for (int f = 0; f < 8; f++)
#pragma unroll
    for (int n = 0; n < 4; n++) acc[f][n] = (f32x4){0.f, 0.f, 0.f, 0.f};
  short8 a_[4], b_[4];

  STAGE_A(0, 0);  STAGE_B(0, 0);
  STAGE_A(1, 32); STAGE_B(1, 32);
  STAGE_A(2, 64); STAGE_B(2, 64);
  VM8;
  SB;
  __builtin_amdgcn_s_barrier();
  SB;

#pragma unroll 4
  for (int kt = 0; kt < 29; ++kt) {          // NT=32, full iterations
    int sl = kt & 3, sl3 = (kt + 3) & 3;
    int koff3 = (kt + 3) * 32;
    PH0(sl, STAGE_A(sl3, koff3));
    PH1(sl, STAGE_B(sl3, koff3), VM8);
  }
  PH0(1, NOP); PH1(1, NOP, VM4);             // kt=29: 8 out -> drain kt30's 4
  PH0(2, NOP); PH1(2, NOP, VM0);             // kt=30: 4 out -> drain kt31's 4
  PH0(3, NOP); PH1(3, NOP, NOP);             // kt=31: nothing outstanding

  const float* b1e = b1 + (size_t)e * HID;
  float bias[4];
#pragma unroll
  for (int n = 0; n < 4; n++) bias[n] = b1e[nb + wc * 64 + n * 16 + cc];
#pragma unroll
  for (int f = 0; f < 8; f++) {
#pragma unroll
    for (int r = 0; r < 4; r++) {
      int m_loc = wr * 128 + f * 16 + q4 * 4 + r;
      int m = m_base + m_loc;
      if (m < cnt) {
        size_t hrow = (size_t)(off_e + m) * HID;
#pragma unroll
        for (int n = 0; n < 4; n++)
          Hbuf[hrow + nb + wc * 64 + n * 16 + cc] = f2bf(fast_gelu(acc[f][n][r] + bias[n]));
      }
    }
  }
}

// ---------- GEMM2 (split-K=2): Yp[s][slot] = H[slot] @ w2[e][kslice] ----------
// grid 1024: e = h&7; s = (h>>3)&1; j = h>>4: m_idx = j&15, n_idx = j>>4 (0..3).
__global__ __launch_bounds__(512, 2) void k_gemm2(
    const unsigned short* __restrict__ Hbuf,
    const unsigned short* __restrict__ w2t,
    const int* __restrict__ ctrl,
    unsigned short* __restrict__ Yp) {
  int h = blockIdx.x;
  int e = h & 7;
  int s = (h >> 3) & 1;
  int j = h >> 4;
  int m_base = (j & 15) * 256;
  int nb = (j >> 4) * 256;
  int cnt = ctrl[e];
  if (m_base >= cnt) return;
  int off_e = ctrl[8 + e];
  int tid = threadIdx.x;
  int wave = tid >> 6, lane = tid & 63;
  int wr = wave >> 2, wc = wave & 3;
  int q4 = lane >> 4, cc = lane & 15;

  __shared__ __align__(16) char lds[131072];

  int chS = (lane & 3) ^ ((lane >> 3) & 3);
  int row0 = wave * 16 + (lane >> 2);
  int row1 = 128 + row0;
  int ar0 = off_e + min(m_base + row0, cnt - 1);
  int ar1 = off_e + min(m_base + row1, cnt - 1);
  int kbeg = s * (HID / 2);
  const unsigned short* sA0 = Hbuf + (size_t)ar0 * HID + kbeg + chS * 8;
  const unsigned short* sA1 = Hbuf + (size_t)ar1 * HID + kbeg + chS * 8;
  const unsigned short* wbp = w2t + (size_t)e * EMBD * HID;
  const unsigned short* sB0 = wbp + (size_t)(nb + row0) * HID + kbeg + chS * 8;
  const unsigned short* sB1 = wbp + (size_t)(nb + row1) * HID + kbeg + chS * 8;

  int swz = (q4 ^ ((cc >> 1) & 3)) * 16;
  int aoff = wr * 8192 + cc * 64 + swz;
  int boff = (wc >> 1) * 8192 + (wc & 1) * 4096 + cc * 64 + swz;

  f32x4 acc[8][4];
#pragma unroll
  for (int f = 0; f < 8; f++)
#pragma unroll
    for (int n = 0; n < 4; n++) acc[f][n] = (f32x4){0.f, 0.f, 0.f, 0.f};
  short8 a_[4], b_[4];

  STAGE_A(0, 0);  STAGE_B(0, 0);
  STAGE_A(1, 32); STAGE_B(1, 32);
  STAGE_A(2, 64); STAGE_B(2, 64);
  VM8;
  SB;
  __builtin_amdgcn_s_barrier();
  SB;

#pragma unroll 4
  for (int kt = 0; kt < 61; ++kt) {          // NT=64, full iterations
    int sl = kt & 3, sl3 = (kt + 3) & 3;
    int koff3 = (kt + 3) * 32;
    PH0(sl, STAGE_A(sl3, koff3));
    PH1(sl, STAGE_B(sl3, koff3), VM8);
  }
  PH0(1, NOP); PH1(1, NOP, VM4);             // kt=61
  PH0(2, NOP); PH1(2, NOP, VM0);             // kt=62
  PH0(3, NOP); PH1(3, NOP, NOP);             // kt=63

  unsigned short* Yps = Yp + (size_t)s * SLOTC * EMBD;
#pragma unroll
  for (int f = 0; f < 8; f++) {
#pragma unroll
    for (int r = 0; r < 4; r++) {
      int m_loc = wr * 128 + f * 16 + q4 * 4 + r;
      int m = m_base + m_loc;
      if (m < cnt) {
        size_t yrow = (size_t)(off_e + m) * EMBD;
#pragma unroll
        for (int n = 0; n < 4; n++)
          Yps[yrow + nb + wc * 64 + n * 16 + cc] = f2bf(acc[f][n][r]);
      }
    }
  }
}

// ---------- combine: out[t] = sum_k wv_k * (b2[e_k] + sum_s Yp[s][slot_k]) ----------
__global__ __launch_bounds__(256) void k_combine(const unsigned short* __restrict__ Yp,
                                                 const float* __restrict__ b2,
                                                 const int* __restrict__ idx2,
                                                 const float* __restrict__ wv,
                                                 const int* __restrict__ tok2slot,
                                                 float* __restrict__ out) {
  int t = blockIdx.x;
  int tid = threadIdx.x;
  int c = tid * 4;
  int e0 = idx2[2 * t], e1 = idx2[2 * t + 1];
  float w0 = wv[2 * t], w1 = wv[2 * t + 1];
  int s0 = tok2slot[2 * t], s1 = tok2slot[2 * t + 1];
  ushort4 p00 = *(const ushort4*)(Yp + ((size_t)0 * SLOTC + s0) * EMBD + c);
  ushort4 p01 = *(const ushort4*)(Yp + ((size_t)1 * SLOTC + s0) * EMBD + c);
  ushort4 p10 = *(const ushort4*)(Yp + ((size_t)0 * SLOTC + s1) * EMBD + c);
  ushort4 p11 = *(const ushort4*)(Yp + ((size_t)1 * SLOTC + s1) * EMBD + c);
  float4 b20 = *(const float4*)(b2 + (size_t)e0 * EMBD + c);
  float4 b21 = *(const float4*)(b2 + (size_t)e1 * EMBD + c);
  float4 r;
  r.x = w0 * (bf2f(p00.x) + bf2f(p01.x) + b20.x) + w1 * (bf2f(p10.x) + bf2f(p11.x) + b21.x);
  r.y = w0 * (bf2f(p00.y) + bf2f(p01.y) + b20.y) + w1 * (bf2f(p10.y) + bf2f(p11.y) + b21.y);
  r.z = w0 * (bf2f(p00.z) + bf2f(p01.z) + b20.z) + w1 * (bf2f(p10.z) + bf2f(p11.z) + b21.z);
  r.w = w0 * (bf2f(p00.w) + bf2f(p01.w) + b20.w) + w1 * (bf2f(p10.w) + bf2f(p11.w) + b21.w);
  *(float4*)(out + (size_t)t * EMBD + c) = r;
}

extern "C" void kernel_launch(void* const* d_in, const int* in_sizes, int n_in,
                              void* d_out, int out_size, void* d_ws, size_t ws_size,
                              hipStream_t stream) {
  (void)in_sizes; (void)n_in; (void)out_size; (void)ws_size;
  const float* x      = (const float*)d_in[0];
  const float* gate_w = (const float*)d_in[1];
  const float* w1     = (const float*)d_in[2];
  const float* b1     = (const float*)d_in[3];
  const float* w2     = (const float*)d_in[4];
  const float* b2     = (const float*)d_in[5];
  float* out = (float*)d_out;

  char* ws = (char*)d_ws;
  size_t off = 0;
  auto alloc = [&](size_t bytes) {
    char* p = ws + off;
    off += (bytes + 255) & ~(size_t)255;
    return p;
  };
  unsigned short* xb    = (unsigned short*)alloc((size_t)TOKENS * EMBD * 2);
  unsigned short* w1t   = (unsigned short*)alloc((size_t)NE * HID * EMBD * 2);
  unsigned short* w2t   = (unsigned short*)alloc((size_t)NE * EMBD * HID * 2);
  unsigned short* Hbuf  = (unsigned short*)alloc((size_t)SLOTC * HID * 2);
  unsigned short* Yp    = (unsigned short*)alloc((size_t)2 * SLOTC * EMBD * 2);
  int*   token_list     = (int*)alloc((size_t)SLOTC * 4);
  int*   idx2           = (int*)alloc((size_t)TOKENS * 2 * 4);
  float* wv             = (float*)alloc((size_t)TOKENS * 2 * 4);
  int*   tok2slot       = (int*)alloc((size_t)TOKENS * 2 * 4);
  int*   ctrl           = (int*)alloc(32 * 4);

  k_gate_cvt<<<TOKENS / 4, 256, 0, stream>>>(x, gate_w, xb, idx2, wv);
  k_count<<<1, 256, 0, stream>>>(idx2, ctrl);
  k_assign<<<TOKENS / 256, 256, 0, stream>>>(idx2, ctrl, token_list, tok2slot);
  k_trans<<<dim3(HID / 64, EMBD / 64, NE), 256, 0, stream>>>(w1, w1t, EMBD, HID);
  k_trans<<<dim3(EMBD / 64, HID / 64, NE), 256, 0, stream>>>(w2, w2t, HID, EMBD);
  k_gemm1<<<2048, 512, 0, stream>>>(xb, w1t, b1, ctrl, token_list, Hbuf);
  k_gemm2<<<1024, 512, 0, stream>>>(Hbuf, w2t, ctrl, Yp);
  k_combine<<<TOKENS, 256, 0, stream>>>(Yp, b2, idx2, wv, tok2slot, out);
}

// Round 5
// 565.981 us; speedup vs baseline: 1.0708x; 1.0708x over previous
//
#include <hip/hip_runtime.h>
#include <math.h>

#define TOKENS 4096
#define EMBD   1024
#define HID    4096
#define NE     8
#define SLOTC  8320   // padded slot capacity (8192 used)

typedef __attribute__((ext_vector_type(8))) short short8;
typedef __attribute__((ext_vector_type(4))) float f32x4;

#define GLOBAL_PTR(p) ((const __attribute__((address_space(1))) void*)(p))
#define LDS_PTR(p)    ((__attribute__((address_space(3))) void*)(p))

__device__ __forceinline__ unsigned short f2bf(float f) {
  unsigned int u = __float_as_uint(f);
  u += 0x7FFFu + ((u >> 16) & 1u);   // round-to-nearest-even
  return (unsigned short)(u >> 16);
}
__device__ __forceinline__ float bf2f(unsigned short h) {
  return __uint_as_float((unsigned int)h << 16);
}

// exact-GELU via Abramowitz-Stegun 7.1.26 erf (|eps| < 1.5e-7), ~12 VALU ops
__device__ __forceinline__ float fast_gelu(float v) {
  float u = fabsf(v) * 0.70710678118654752f;
  float t = 1.0f / (1.0f + 0.3275911f * u);
  float poly = ((((1.061405429f * t - 1.453152027f) * t + 1.421413741f) * t
                 - 0.284496736f) * t + 0.254829592f) * t;
  float erf_abs = 1.0f - poly * __expf(-u * u);
  float er = (v < 0.0f) ? -erf_abs : erf_abs;
  return 0.5f * v * (1.0f + er);
}

// ---------- fused gate + x fp32->bf16 convert. One wave per token. ----------
__global__ __launch_bounds__(256) void k_gate_cvt(const float* __restrict__ x,
                                                  const float* __restrict__ gw,
                                                  unsigned short* __restrict__ xb,
                                                  int* __restrict__ idx2,
                                                  float* __restrict__ wv) {
  int wave = threadIdx.x >> 6, lane = threadIdx.x & 63;
  int t = blockIdx.x * 4 + wave;
  const float4* xr = (const float4*)(x + (size_t)t * EMBD);   // 256 float4
  ushort4* xbr = (ushort4*)(xb + (size_t)t * EMBD);
  float acc[NE];
#pragma unroll
  for (int e = 0; e < NE; e++) acc[e] = 0.f;
#pragma unroll
  for (int ch = 0; ch < 4; ch++) {
    int i = ch * 64 + lane;
    float4 v = xr[i];
    ushort4 o;
    o.x = f2bf(v.x); o.y = f2bf(v.y); o.z = f2bf(v.z); o.w = f2bf(v.w);
    xbr[i] = o;
    int c = i * 4;
    const float* g0 = gw + (size_t)c * NE;
#pragma unroll
    for (int e = 0; e < NE; e++) acc[e] += v.x * g0[e];
#pragma unroll
    for (int e = 0; e < NE; e++) acc[e] += v.y * g0[NE + e];
#pragma unroll
    for (int e = 0; e < NE; e++) acc[e] += v.z * g0[2 * NE + e];
#pragma unroll
    for (int e = 0; e < NE; e++) acc[e] += v.w * g0[3 * NE + e];
  }
#pragma unroll
  for (int e = 0; e < NE; e++) {
#pragma unroll
    for (int off = 32; off > 0; off >>= 1) acc[e] += __shfl_down(acc[e], off);
  }
  if (lane == 0) {
    float best = -1e30f, second = -1e30f;
    int bi = 0, si = 0;
#pragma unroll
    for (int e = 0; e < NE; e++) {
      float l = acc[e];
      if (l > best) { second = best; si = bi; best = l; bi = e; }
      else if (l > second) { second = l; si = e; }
    }
    float b = expf(second - best);
    float w0 = 1.f / (1.f + b);
    float w1 = b / (1.f + b);
    idx2[2 * t] = bi; idx2[2 * t + 1] = si;
    wv[2 * t] = w0; wv[2 * t + 1] = w1;
  }
}

// ---------- histogram + prefix in one tiny kernel ----------
__global__ __launch_bounds__(256) void k_count(const int* __restrict__ idx2,
                                               int* __restrict__ ctrl) {
  __shared__ int cnt[NE];
  int tid = threadIdx.x;
  if (tid < NE) cnt[tid] = 0;
  __syncthreads();
  for (int i = tid; i < TOKENS * 2; i += 256) atomicAdd(&cnt[idx2[i]], 1);
  __syncthreads();
  if (tid == 0) {
    int off = 0;
#pragma unroll
    for (int e = 0; e < NE; e++) { int c = cnt[e]; ctrl[e] = c; ctrl[8 + e] = off; off += c; }
    ctrl[16] = off;
  }
  if (tid < NE) ctrl[17 + tid] = 0;
}

// ---------- slot assignment: two-level (LDS positions, 8 global atomics/blk) ---
__global__ __launch_bounds__(256) void k_assign(const int* __restrict__ idx2,
                                                int* __restrict__ ctrl,
                                                int* __restrict__ token_list,
                                                int* __restrict__ tok2slot) {
  __shared__ int lpos[NE];
  __shared__ int lbase[NE];
  int tid = threadIdx.x;
  int t = blockIdx.x * 256 + tid;
  if (tid < NE) lpos[tid] = 0;
  __syncthreads();
  int e0 = idx2[2 * t], e1 = idx2[2 * t + 1];
  int p0 = atomicAdd(&lpos[e0], 1);
  int p1 = atomicAdd(&lpos[e1], 1);
  __syncthreads();
  if (tid < NE) lbase[tid] = atomicAdd(&ctrl[17 + tid], lpos[tid]);
  __syncthreads();
  int s0 = ctrl[8 + e0] + lbase[e0] + p0;
  int s1 = ctrl[8 + e1] + lbase[e1] + p1;
  token_list[s0] = t;
  token_list[s1] = t;
  tok2slot[2 * t] = s0;
  tok2slot[2 * t + 1] = s1;
}

// ---------- transpose+convert: in [e][R][C] fp32 -> out [e][C][R] bf16 ----------
__global__ __launch_bounds__(256) void k_trans(const float* __restrict__ in,
                                               unsigned short* __restrict__ out,
                                               int R, int C) {
  __shared__ unsigned short T[64 * 66];   // [col][row], pad 66
  int e = blockIdx.z;
  const float* ine = in + (size_t)e * R * C;
  unsigned short* oute = out + (size_t)e * R * C;
  int r0 = blockIdx.y * 64;
  int c0 = blockIdx.x * 64;
  int tid = threadIdx.x;
  {
    int c4 = tid & 15;          // float4 col chunk
    int rb = tid >> 4;          // 0..15
#pragma unroll
    for (int it = 0; it < 4; it++) {
      int r = rb + 16 * it;
      float4 v = *(const float4*)(ine + (size_t)(r0 + r) * C + c0 + 4 * c4);
      T[(4 * c4 + 0) * 66 + r] = f2bf(v.x);
      T[(4 * c4 + 1) * 66 + r] = f2bf(v.y);
      T[(4 * c4 + 2) * 66 + r] = f2bf(v.z);
      T[(4 * c4 + 3) * 66 + r] = f2bf(v.w);
    }
  }
  __syncthreads();
  {
    int rr = tid & 7;           // 16B chunk along output row
    int cq = tid >> 3;          // 0..31
#pragma unroll
    for (int it = 0; it < 2; it++) {
      int c = cq + 32 * it;     // output row (= input col)
      short8 o;
#pragma unroll
      for (int k = 0; k < 8; k++) o[k] = (short)T[c * 66 + 8 * rr + k];
      *(short8*)(oute + (size_t)(c0 + c) * R + r0 + 8 * rr) = o;
    }
  }
}

// =====================================================================
// 128x128 grouped GEMM (r1 structure: measured-best TLP of ~3 blocks/CU)
// + 3-slot LDS ring (48 KB), counted vmcnt(4), 2-iter lookahead, ONE
// barrier per K-tile. Per iter:
//   vmcnt(4) gate (tile kt landed; kt+1 in flight)  [per-wave]
//   s_barrier (now block-wide visible; also retires slot (kt+2)%3 reads)
//   stage(kt+2) -> slot (kt+2)%3   [issued before compute]
//   ds_read slot kt%3 (compiler-scheduled lgkmcnt) -> 16 MFMA
// Tail: kt=NT-1 gates vmcnt(0); stage skipped for kt+2 >= NT (uniform).
// Swizzle (PMC-verified 0-conflict): stored chunk s holds global chunk
// s ^ ((row>>1)&3); staging fetches chS = (lane&3)^((lane>>3)&3).
// =====================================================================

#define SB __builtin_amdgcn_sched_barrier(0)
#define VM4 asm volatile("s_waitcnt vmcnt(4)" ::: "memory")
#define VM0 asm volatile("s_waitcnt vmcnt(0)" ::: "memory")

#define STAGE_T(sl, koff) do {                                                                                   \
    __builtin_amdgcn_global_load_lds(GLOBAL_PTR(sA0 + (koff)), LDS_PTR(lds + (sl) * 16384 + wave * 1024), 16, 0, 0);          \
    __builtin_amdgcn_global_load_lds(GLOBAL_PTR(sA1 + (koff)), LDS_PTR(lds + (sl) * 16384 + 4096 + wave * 1024), 16, 0, 0);   \
    __builtin_amdgcn_global_load_lds(GLOBAL_PTR(sB0 + (koff)), LDS_PTR(lds + (sl) * 16384 + 8192 + wave * 1024), 16, 0, 0);   \
    __builtin_amdgcn_global_load_lds(GLOBAL_PTR(sB1 + (koff)), LDS_PTR(lds + (sl) * 16384 + 12288 + wave * 1024), 16, 0, 0);  \
  } while (0)

#define KLOOP(NT) do {                                                                            \
    int sl = 0, sl2 = 2;                                                                          \
    for (int kt = 0; kt < (NT); ++kt) {                                                           \
      if (kt < (NT) - 1) { VM4; } else { VM0; }                                                   \
      SB;                                                                                         \
      __builtin_amdgcn_s_barrier();                                                               \
      SB;                                                                                         \
      if (kt + 2 < (NT)) STAGE_T(sl2, (kt + 2) * 32);                                             \
      SB;                                                                                         \
      const char* Ab_ = lds + sl * 16384;                                                         \
      const char* Bb_ = Ab_ + 8192;                                                               \
      short8 af[4], bg[4];                                                                        \
      _Pragma("unroll")                                                                           \
      for (int i = 0; i < 4; i++) af[i] = *(const short8*)(Ab_ + aoff + i * 1024);                \
      _Pragma("unroll")                                                                           \
      for (int n = 0; n < 4; n++) bg[n] = *(const short8*)(Bb_ + boff + n * 1024);                \
      _Pragma("unroll")                                                                           \
      for (int i = 0; i < 4; i++)                                                                 \
        _Pragma("unroll")                                                                         \
        for (int n = 0; n < 4; n++)                                                               \
          acc[i][n] = __builtin_amdgcn_mfma_f32_16x16x32_bf16(af[i], bg[n], acc[i][n], 0, 0, 0);  \
      sl = (sl == 2) ? 0 : sl + 1;                                                                \
      sl2 = (sl2 == 2) ? 0 : sl2 + 1;                                                             \
    }                                                                                             \
  } while (0)

// ---------- GEMM1: H = gelu(gather(x) @ w1[e] + b1[e]) ----------
// grid 8192: e = h&7 (XCD-keyed); j = h>>3: m_idx = j&31 (fastest: the ~8
// active m-blocks of one n-panel run concurrently -> B L2 reuse), n = j>>5.
__global__ __launch_bounds__(256, 3) void k_gemm1(
    const unsigned short* __restrict__ xb,
    const unsigned short* __restrict__ w1t,
    const float* __restrict__ b1,
    const int* __restrict__ ctrl,
    const int* __restrict__ token_list,
    unsigned short* __restrict__ Hbuf) {
  int h = blockIdx.x;
  int e = h & 7;
  int j = h >> 3;
  int m_base = (j & 31) * 128;
  int nb = (j >> 5) * 128;
  int cnt = ctrl[e];
  if (m_base >= cnt) return;
  int off_e = ctrl[8 + e];
  int tid = threadIdx.x;
  int wave = tid >> 6, lane = tid & 63;

  __shared__ __align__(16) char lds[49152];   // 3 slots x (A 8KB + B 8KB)

  // staging sources (loop-invariant)
  int chS = (lane & 3) ^ ((lane >> 3) & 3);
  int rowA0 = tid >> 2;            // rows 0..63
  int rowA1 = 64 + rowA0;          // rows 64..127
  int tok0 = token_list[off_e + min(m_base + rowA0, cnt - 1)];
  int tok1 = token_list[off_e + min(m_base + rowA1, cnt - 1)];
  const unsigned short* sA0 = xb + (size_t)tok0 * EMBD + chS * 8;
  const unsigned short* sA1 = xb + (size_t)tok1 * EMBD + chS * 8;
  const unsigned short* wbp = w1t + (size_t)e * HID * EMBD;
  const unsigned short* sB0 = wbp + (size_t)(nb + rowA0) * EMBD + chS * 8;
  const unsigned short* sB1 = wbp + (size_t)(nb + rowA1) * EMBD + chS * 8;

  int wm = (wave >> 1) * 64, wn = (wave & 1) * 64;
  int q4 = lane >> 4, cc = lane & 15;
  int swz = (q4 ^ ((cc >> 1) & 3)) * 16;
  int aoff = (wm + cc) * 64 + swz;   // bytes within slot A region
  int boff = (wn + cc) * 64 + swz;   // bytes within slot B region

  f32x4 acc[4][4];
#pragma unroll
  for (int i = 0; i < 4; i++)
#pragma unroll
    for (int n = 0; n < 4; n++) acc[i][n] = (f32x4){0.f, 0.f, 0.f, 0.f};

  STAGE_T(0, 0);
  STAGE_T(1, 32);
  KLOOP(32);

  const float* b1e = b1 + (size_t)e * HID;
  float bias[4];
#pragma unroll
  for (int n = 0; n < 4; n++) bias[n] = b1e[nb + wn + n * 16 + cc];
#pragma unroll
  for (int i = 0; i < 4; i++) {
#pragma unroll
    for (int r = 0; r < 4; r++) {
      int m_loc = wm + i * 16 + q4 * 4 + r;
      int m = m_base + m_loc;
      if (m < cnt) {
        size_t hrow = (size_t)(off_e + m) * HID;
#pragma unroll
        for (int n = 0; n < 4; n++)
          Hbuf[hrow + nb + wn + n * 16 + cc] = f2bf(fast_gelu(acc[i][n][r] + bias[n]));
      }
    }
  }
}

// ---------- GEMM2 (split-K=2): Yp[s][slot] = H[slot] @ w2[e][kslice] ----------
// grid 4096: e = h&7; s = (h>>3)&1; rem = h>>4: m_idx = rem&31 (fastest), n = rem>>5.
__global__ __launch_bounds__(256, 3) void k_gemm2(
    const unsigned short* __restrict__ Hbuf,
    const unsigned short* __restrict__ w2t,
    const int* __restrict__ ctrl,
    unsigned short* __restrict__ Yp) {
  int h = blockIdx.x;
  int e = h & 7;
  int s = (h >> 3) & 1;
  int rem = h >> 4;
  int m_base = (rem & 31) * 128;
  int nb = (rem >> 5) * 128;
  int cnt = ctrl[e];
  if (m_base >= cnt) return;
  int off_e = ctrl[8 + e];
  int tid = threadIdx.x;
  int wave = tid >> 6, lane = tid & 63;

  __shared__ __align__(16) char lds[49152];

  int chS = (lane & 3) ^ ((lane >> 3) & 3);
  int rowA0 = tid >> 2;
  int rowA1 = 64 + rowA0;
  int ar0 = off_e + min(m_base + rowA0, cnt - 1);
  int ar1 = off_e + min(m_base + rowA1, cnt - 1);
  int kbeg = s * (HID / 2);
  const unsigned short* sA0 = Hbuf + (size_t)ar0 * HID + kbeg + chS * 8;
  const unsigned short* sA1 = Hbuf + (size_t)ar1 * HID + kbeg + chS * 8;
  const unsigned short* wbp = w2t + (size_t)e * EMBD * HID;
  const unsigned short* sB0 = wbp + (size_t)(nb + rowA0) * HID + kbeg + chS * 8;
  const unsigned short* sB1 = wbp + (size_t)(nb + rowA1) * HID + kbeg + chS * 8;

  int wm = (wave >> 1) * 64, wn = (wave & 1) * 64;
  int q4 = lane >> 4, cc = lane & 15;
  int swz = (q4 ^ ((cc >> 1) & 3)) * 16;
  int aoff = (wm + cc) * 64 + swz;
  int boff = (wn + cc) * 64 + swz;

  f32x4 acc[4][4];
#pragma unroll
  for (int i = 0; i < 4; i++)
#pragma unroll
    for (int n = 0; n < 4; n++) acc[i][n] = (f32x4){0.f, 0.f, 0.f, 0.f};

  STAGE_T(0, 0);
  STAGE_T(1, 32);
  KLOOP(64);

  unsigned short* Yps = Yp + (size_t)s * SLOTC * EMBD;
#pragma unroll
  for (int i = 0; i < 4; i++) {
#pragma unroll
    for (int r = 0; r < 4; r++) {
      int m_loc = wm + i * 16 + q4 * 4 + r;
      int m = m_base + m_loc;
      if (m < cnt) {
        size_t yrow = (size_t)(off_e + m) * EMBD;
#pragma unroll
        for (int n = 0; n < 4; n++)
          Yps[yrow + nb + wn + n * 16 + cc] = f2bf(acc[i][n][r]);
      }
    }
  }
}

// ---------- combine: out[t] = sum_k wv_k * (b2[e_k] + sum_s Yp[s][slot_k]) ----------
__global__ __launch_bounds__(256) void k_combine(const unsigned short* __restrict__ Yp,
                                                 const float* __restrict__ b2,
                                                 const int* __restrict__ idx2,
                                                 const float* __restrict__ wv,
                                                 const int* __restrict__ tok2slot,
                                                 float* __restrict__ out) {
  int t = blockIdx.x;
  int tid = threadIdx.x;
  int c = tid * 4;
  int e0 = idx2[2 * t], e1 = idx2[2 * t + 1];
  float w0 = wv[2 * t], w1 = wv[2 * t + 1];
  int s0 = tok2slot[2 * t], s1 = tok2slot[2 * t + 1];
  ushort4 p00 = *(const ushort4*)(Yp + ((size_t)0 * SLOTC + s0) * EMBD + c);
  ushort4 p01 = *(const ushort4*)(Yp + ((size_t)1 * SLOTC + s0) * EMBD + c);
  ushort4 p10 = *(const ushort4*)(Yp + ((size_t)0 * SLOTC + s1) * EMBD + c);
  ushort4 p11 = *(const ushort4*)(Yp + ((size_t)1 * SLOTC + s1) * EMBD + c);
  float4 b20 = *(const float4*)(b2 + (size_t)e0 * EMBD + c);
  float4 b21 = *(const float4*)(b2 + (size_t)e1 * EMBD + c);
  float4 r;
  r.x = w0 * (bf2f(p00.x) + bf2f(p01.x) + b20.x) + w1 * (bf2f(p10.x) + bf2f(p11.x) + b21.x);
  r.y = w0 * (bf2f(p00.y) + bf2f(p01.y) + b20.y) + w1 * (bf2f(p10.y) + bf2f(p11.y) + b21.y);
  r.z = w0 * (bf2f(p00.z) + bf2f(p01.z) + b20.z) + w1 * (bf2f(p10.z) + bf2f(p11.z) + b21.z);
  r.w = w0 * (bf2f(p00.w) + bf2f(p01.w) + b20.w) + w1 * (bf2f(p10.w) + bf2f(p11.w) + b21.w);
  *(float4*)(out + (size_t)t * EMBD + c) = r;
}

extern "C" void kernel_launch(void* const* d_in, const int* in_sizes, int n_in,
                              void* d_out, int out_size, void* d_ws, size_t ws_size,
                              hipStream_t stream) {
  (void)in_sizes; (void)n_in; (void)out_size; (void)ws_size;
  const float* x      = (const float*)d_in[0];
  const float* gate_w = (const float*)d_in[1];
  const float* w1     = (const float*)d_in[2];
  const float* b1     = (const float*)d_in[3];
  const float* w2     = (const float*)d_in[4];
  const float* b2     = (const float*)d_in[5];
  float* out = (float*)d_out;

  char* ws = (char*)d_ws;
  size_t off = 0;
  auto alloc = [&](size_t bytes) {
    char* p = ws + off;
    off += (bytes + 255) & ~(size_t)255;
    return p;
  };
  unsigned short* xb    = (unsigned short*)alloc((size_t)TOKENS * EMBD * 2);
  unsigned short* w1t   = (unsigned short*)alloc((size_t)NE * HID * EMBD * 2);
  unsigned short* w2t   = (unsigned short*)alloc((size_t)NE * EMBD * HID * 2);
  unsigned short* Hbuf  = (unsigned short*)alloc((size_t)SLOTC * HID * 2);
  unsigned short* Yp    = (unsigned short*)alloc((size_t)2 * SLOTC * EMBD * 2);
  int*   token_list     = (int*)alloc((size_t)SLOTC * 4);
  int*   idx2           = (int*)alloc((size_t)TOKENS * 2 * 4);
  float* wv             = (float*)alloc((size_t)TOKENS * 2 * 4);
  int*   tok2slot       = (int*)alloc((size_t)TOKENS * 2 * 4);
  int*   ctrl           = (int*)alloc(32 * 4);

  k_gate_cvt<<<TOKENS / 4, 256, 0, stream>>>(x, gate_w, xb, idx2, wv);
  k_count<<<1, 256, 0, stream>>>(idx2, ctrl);
  k_assign<<<TOKENS / 256, 256, 0, stream>>>(idx2, ctrl, token_list, tok2slot);
  k_trans<<<dim3(HID / 64, EMBD / 64, NE), 256, 0, stream>>>(w1, w1t, EMBD, HID);
  k_trans<<<dim3(EMBD / 64, HID / 64, NE), 256, 0, stream>>>(w2, w2t, HID, EMBD);
  k_gemm1<<<8192, 256, 0, stream>>>(xb, w1t, b1, ctrl, token_list, Hbuf);
  k_gemm2<<<4096, 256, 0, stream>>>(Hbuf, w2t, ctrl, Yp);
  k_combine<<<TOKENS, 256, 0, stream>>>(Yp, b2, idx2, wv, tok2slot, out);
}